// Round 1
// baseline (148.881 us; speedup 1.0000x reference)
//
#include <hip/hip_runtime.h>
#include <hip/hip_bf16.h>

#define BB 8
#define CC 128
#define HH 192
#define WW 192
#define HWSZ (HH*WW)
#define KK 1024
#define HALF 3
#define GOUT 32

// ---------- Kernel 1: peak flags (local max of 3x3, value > 0) ----------
__global__ void k_flags(const float* __restrict__ hm, unsigned char* __restrict__ flags) {
    int idx = blockIdx.x * blockDim.x + threadIdx.x;
    if (idx >= BB * HWSZ) return;
    int b = idx / HWSZ;
    int p = idx % HWSZ;
    int y = p / WW, x = p % WW;
    const float* h = hm + (size_t)b * HWSZ;
    float v = h[p];
    unsigned char f = 0;
    if (v > 0.f) {
        bool peak = true;
        #pragma unroll
        for (int dy = -1; dy <= 1; ++dy) {
            #pragma unroll
            for (int dx = -1; dx <= 1; ++dx) {
                int yy = y + dy, xx = x + dx;
                if (yy < 0 || yy >= HH || xx < 0 || xx >= WW) continue;
                if (h[yy * WW + xx] > v) peak = false;
            }
        }
        f = peak ? 1 : 0;
    }
    flags[idx] = f;
}

// ---------- Kernel 2: deterministic ordered compaction (1 wave / image) ----------
__global__ __launch_bounds__(64) void k_compact(const unsigned char* __restrict__ flags,
                                                int* __restrict__ peaks,
                                                int* __restrict__ count) {
    int b = blockIdx.x;
    int lane = threadIdx.x;  // 0..63
    const unsigned char* f = flags + (size_t)b * HWSZ;
    int base = 0;
    // HWSZ = 36864 = 36 * 1024; each wave iteration covers 1024 flags (16/lane)
    for (int it = 0; it < HWSZ / 1024; ++it) {
        uint4 v = *reinterpret_cast<const uint4*>(f + it * 1024 + lane * 16);
        unsigned int wv[4] = {v.x, v.y, v.z, v.w};
        int cnt = 0;
        #pragma unroll
        for (int q = 0; q < 4; ++q) cnt += __popc(wv[q] & 0x01010101u);
        // inclusive wave scan of cnt
        int incl = cnt;
        #pragma unroll
        for (int d = 1; d < 64; d <<= 1) {
            int t = __shfl_up(incl, d);
            if (lane >= d) incl += t;
        }
        int s = base + (incl - cnt);  // exclusive prefix + running base
        int pbase = it * 1024 + lane * 16;
        #pragma unroll
        for (int q = 0; q < 4; ++q) {
            unsigned int w = wv[q];
            #pragma unroll
            for (int j = 0; j < 4; ++j) {
                if ((w >> (8 * j)) & 1u) {
                    if (s < KK) peaks[b * KK + s] = pbase + q * 4 + j;
                    ++s;
                }
            }
        }
        base += __shfl(incl, 63);
    }
    if (lane == 0) count[b] = (base < KK) ? base : KK;
}

// ---------- Kernel 3: per-peak region means + intra-region norm ----------
__global__ __launch_bounds__(64) void k_region(const float* __restrict__ fm,
                                               const int* __restrict__ peaks,
                                               const int* __restrict__ count,
                                               float* __restrict__ means,
                                               float* __restrict__ per_region) {
    int b = blockIdx.x / KK;
    int k = blockIdx.x % KK;
    if (k >= count[b]) return;
    int p = peaks[b * KK + k];
    int r = p / WW, c = p % WW;  // row, col of peak; reference swaps them below
    int lane = threadIdx.x;
    const float* F = fm + (size_t)b * CC * HWSZ;
    __shared__ float ms[49];
    // pass 1: channel means per region position (note x/y swap: rows from c, cols from r)
    if (lane < 49) {
        int a = lane / 7, bb2 = lane % 7;
        int frow = c + a - HALF;
        int fcol = r + bb2 - HALF;
        float m = 0.f;
        if (frow >= 0 && frow < HH && fcol >= 0 && fcol < WW) {
            const float* q = F + frow * WW + fcol;
            float s = 0.f;
            #pragma unroll 8
            for (int ch = 0; ch < CC; ++ch) s += q[(size_t)ch * HWSZ];
            m = s * (1.0f / CC);
        }
        ms[lane] = m;
        means[((size_t)b * KK + k) * 49 + lane] = m;
    }
    __syncthreads();
    // pass 2: per-channel intra-region L2 norm; lane handles channels lane and lane+64
    float acc = 0.f;
    #pragma unroll
    for (int half = 0; half < 2; ++half) {
        int ch = lane + half * 64;
        const float* q = F + (size_t)ch * HWSZ;
        float d2 = 0.f;
        #pragma unroll
        for (int pos = 0; pos < 49; ++pos) {
            int a = pos / 7, bb2 = pos % 7;
            int frow = c + a - HALF, fcol = r + bb2 - HALF;
            if (frow >= 0 && frow < HH && fcol >= 0 && fcol < WW) {
                float d = q[frow * WW + fcol] - ms[pos];
                d2 += d * d;
            }
        }
        acc += (d2 > 0.f) ? sqrtf(d2) : 0.f;
    }
    #pragma unroll
    for (int d = 32; d > 0; d >>= 1) acc += __shfl_down(acc, d);
    if (lane == 0) per_region[b * KK + k] = acc * (1.0f / CC);
}

// ---------- Kernel 4: intra loss per image ----------
__global__ __launch_bounds__(256) void k_loss_in(const float* __restrict__ per_region,
                                                 const int* __restrict__ count,
                                                 float* __restrict__ loss_in) {
    int b = blockIdx.x;
    int n = count[b];
    __shared__ float sm[256];
    float s = 0.f;
    for (int k = threadIdx.x; k < n; k += 256) s += per_region[b * KK + k];
    sm[threadIdx.x] = s;
    __syncthreads();
    for (int d = 128; d > 0; d >>= 1) {
        if (threadIdx.x < d) sm[threadIdx.x] += sm[threadIdx.x + d];
        __syncthreads();
    }
    if (threadIdx.x == 0) loss_in[b] = (n > 0) ? sm[0] / (float)n : 0.f;
}

// ---------- Kernel 5: pairwise hinge partials (GOUT blocks / image) ----------
__global__ __launch_bounds__(256) void k_pairs(const float* __restrict__ means,
                                               const int* __restrict__ count,
                                               float* __restrict__ partial) {
    int b = blockIdx.x / GOUT;
    int g = blockIdx.x % GOUT;
    int n = count[b];
    const float* mf = means + (size_t)b * KK * 49;
    __shared__ float mi[49];
    __shared__ float sm[256];
    float acc = 0.f;
    for (int i = g; i < n; i += GOUT) {
        __syncthreads();
        if (threadIdx.x < 49) mi[threadIdx.x] = mf[(size_t)i * 49 + threadIdx.x];
        __syncthreads();
        for (int j = i + 1 + (int)threadIdx.x; j < n; j += 256) {
            const float* mj = mf + (size_t)j * 49;
            float d2 = 0.f;
            #pragma unroll
            for (int d = 0; d < 49; ++d) {
                float t = mi[d] - mj[d];
                d2 += t * t;
            }
            float dd = sqrtf(d2);
            if (dd < 1.f) acc += 1.f - dd;
        }
    }
    sm[threadIdx.x] = acc;
    __syncthreads();
    for (int d = 128; d > 0; d >>= 1) {
        if (threadIdx.x < d) sm[threadIdx.x] += sm[threadIdx.x + d];
        __syncthreads();
    }
    if (threadIdx.x == 0) partial[b * GOUT + g] = sm[0];
}

// ---------- Kernel 6: finalize ----------
__global__ __launch_bounds__(64) void k_final(const float* __restrict__ loss_in,
                                              const float* __restrict__ partial,
                                              const int* __restrict__ count,
                                              float* __restrict__ out) {
    int lane = threadIdx.x;
    float li = 0.f, lo = 0.f;
    if (lane < BB) {
        li = loss_in[lane];
        float s = 0.f;
        #pragma unroll
        for (int g = 0; g < GOUT; ++g) s += partial[lane * GOUT + g];
        float n = (float)count[lane];
        float npairs = n * (n - 1.f) * 0.5f;
        lo = (npairs > 0.f) ? s / npairs : 0.f;
    }
    #pragma unroll
    for (int d = 4; d > 0; d >>= 1) {
        li += __shfl_down(li, d);
        lo += __shfl_down(lo, d);
    }
    if (lane == 0) out[0] = 0.5f * (li * (1.0f / BB)) + 1.0f * (lo * (1.0f / BB));
}

extern "C" void kernel_launch(void* const* d_in, const int* in_sizes, int n_in,
                              void* d_out, int out_size, void* d_ws, size_t ws_size,
                              hipStream_t stream) {
    const float* fm = (const float*)d_in[0];   // [8,128,192,192] f32
    const float* hm = (const float*)d_in[1];   // [8,1,192,192]  f32
    float* out = (float*)d_out;

    char* ws = (char*)d_ws;
    size_t off = 0;
    auto alloc = [&](size_t bytes) -> void* {
        void* p = ws + off;
        off += (bytes + 255) & ~(size_t)255;
        return p;
    };
    unsigned char* flags = (unsigned char*)alloc((size_t)BB * HWSZ);           // 288 KB
    int* peaks          = (int*)alloc((size_t)BB * KK * sizeof(int));          // 32 KB
    int* count          = (int*)alloc((size_t)BB * sizeof(int));
    float* means        = (float*)alloc((size_t)BB * KK * 49 * sizeof(float)); // 1.57 MB
    float* per_region   = (float*)alloc((size_t)BB * KK * sizeof(float));      // 32 KB
    float* loss_in      = (float*)alloc((size_t)BB * sizeof(float));
    float* partial      = (float*)alloc((size_t)BB * GOUT * sizeof(float));

    k_flags<<<(BB * HWSZ + 255) / 256, 256, 0, stream>>>(hm, flags);
    k_compact<<<BB, 64, 0, stream>>>(flags, peaks, count);
    k_region<<<BB * KK, 64, 0, stream>>>(fm, peaks, count, means, per_region);
    k_loss_in<<<BB, 256, 0, stream>>>(per_region, count, loss_in);
    k_pairs<<<BB * GOUT, 256, 0, stream>>>(means, count, partial);
    k_final<<<1, 64, 0, stream>>>(loss_in, partial, count, out);
}

// Round 2
// 128.438 us; speedup vs baseline: 1.1592x; 1.1592x over previous
//
#include <hip/hip_runtime.h>
#include <hip/hip_bf16.h>

#define BB 8
#define CC 128
#define HH 192
#define WW 192
#define HWSZ (HH*WW)
#define KK 1024
#define HALF 3
#define GOUT 32
#define LDP 129   // padded channel stride: bank = (pos+ch)%32 -> <=2-way (free)

// ---------- Kernel 1: peak flags (local max of 3x3, value > 0) ----------
__global__ void k_flags(const float* __restrict__ hm, unsigned char* __restrict__ flags) {
    int idx = blockIdx.x * blockDim.x + threadIdx.x;
    if (idx >= BB * HWSZ) return;
    int b = idx / HWSZ;
    int p = idx % HWSZ;
    int y = p / WW, x = p % WW;
    const float* h = hm + (size_t)b * HWSZ;
    float v = h[p];
    unsigned char f = 0;
    if (v > 0.f) {
        bool peak = true;
        #pragma unroll
        for (int dy = -1; dy <= 1; ++dy) {
            #pragma unroll
            for (int dx = -1; dx <= 1; ++dx) {
                int yy = y + dy, xx = x + dx;
                if (yy < 0 || yy >= HH || xx < 0 || xx >= WW) continue;
                if (h[yy * WW + xx] > v) peak = false;
            }
        }
        f = peak ? 1 : 0;
    }
    flags[idx] = f;
}

// ---------- Kernel 2: deterministic ordered compaction (1 wave / image) ----------
__global__ __launch_bounds__(64) void k_compact(const unsigned char* __restrict__ flags,
                                                int* __restrict__ peaks,
                                                int* __restrict__ count) {
    int b = blockIdx.x;
    int lane = threadIdx.x;  // 0..63
    const unsigned char* f = flags + (size_t)b * HWSZ;
    int base = 0;
    // HWSZ = 36864 = 36 * 1024; each wave iteration covers 1024 flags (16/lane)
    uint4 pre = *reinterpret_cast<const uint4*>(f + lane * 16);
    for (int it = 0; it < HWSZ / 1024; ++it) {
        uint4 v = pre;
        if (it + 1 < HWSZ / 1024)
            pre = *reinterpret_cast<const uint4*>(f + (it + 1) * 1024 + lane * 16);
        unsigned int wv[4] = {v.x, v.y, v.z, v.w};
        int cnt = 0;
        #pragma unroll
        for (int q = 0; q < 4; ++q) cnt += __popc(wv[q] & 0x01010101u);
        // inclusive wave scan of cnt
        int incl = cnt;
        #pragma unroll
        for (int d = 1; d < 64; d <<= 1) {
            int t = __shfl_up(incl, d);
            if (lane >= d) incl += t;
        }
        int s = base + (incl - cnt);  // exclusive prefix + running base
        int pbase = it * 1024 + lane * 16;
        #pragma unroll
        for (int q = 0; q < 4; ++q) {
            unsigned int w = wv[q];
            #pragma unroll
            for (int j = 0; j < 4; ++j) {
                if ((w >> (8 * j)) & 1u) {
                    if (s < KK) peaks[b * KK + s] = pbase + q * 4 + j;
                    ++s;
                }
            }
        }
        base += __shfl(incl, 63);
    }
    if (lane == 0) count[b] = (base < KK) ? base : KK;
}

// ---------- Kernel 3: per-peak region (single global pass, LDS-staged) ----------
__global__ __launch_bounds__(128) void k_region(const float* __restrict__ fm,
                                                const int* __restrict__ peaks,
                                                const int* __restrict__ count,
                                                float* __restrict__ means,
                                                float* __restrict__ per_region) {
    int b = blockIdx.x / KK;
    int k = blockIdx.x % KK;
    if (k >= count[b]) return;
    int p = peaks[b * KK + k];
    int r = p / WW, c = p % WW;  // row, col of peak; reference swaps them (verified r1)
    int tid = threadIdx.x;       // 0..127 == channel
    const float* F = fm + (size_t)b * CC * HWSZ;

    __shared__ float lds[49 * LDP];   // [pos][ch], padded
    __shared__ float pm[49][2];
    __shared__ float ms[49];
    __shared__ float sm[128];

    // stage: thread = channel, 49 independent scattered loads -> LDS
    {
        const float* q = F + (size_t)tid * HWSZ;
        #pragma unroll
        for (int a = 0; a < 7; ++a) {
            int frow = c + a - HALF;
            bool rok = (frow >= 0) & (frow < HH);
            #pragma unroll
            for (int bb2 = 0; bb2 < 7; ++bb2) {
                int fcol = r + bb2 - HALF;
                float v = 0.f;
                if (rok && fcol >= 0 && fcol < WW) v = q[frow * WW + fcol];
                lds[(a * 7 + bb2) * LDP + tid] = v;
            }
        }
    }
    __syncthreads();

    // means: 98 threads, each sums a 64-channel half for one position
    if (tid < 98) {
        int pos = tid >> 1, half = tid & 1;
        const float* row = lds + pos * LDP + half * 64;
        float s = 0.f;
        #pragma unroll 16
        for (int ch = 0; ch < 64; ++ch) s += row[ch];
        pm[pos][half] = s;
    }
    __syncthreads();
    if (tid < 49) {
        float m = (pm[tid][0] + pm[tid][1]) * (1.0f / CC);
        ms[tid] = m;
        means[((size_t)b * KK + k) * 49 + tid] = m;
    }
    __syncthreads();

    // d2 per channel from LDS (mean reads broadcast)
    float d2 = 0.f;
    #pragma unroll
    for (int pos = 0; pos < 49; ++pos) {
        float d = lds[pos * LDP + tid] - ms[pos];
        d2 += d * d;
    }
    float acc = (d2 > 0.f) ? sqrtf(d2) : 0.f;

    sm[tid] = acc;
    __syncthreads();
    #pragma unroll
    for (int d = 64; d > 0; d >>= 1) {
        if (tid < d) sm[tid] += sm[tid + d];
        __syncthreads();
    }
    if (tid == 0) per_region[b * KK + k] = sm[0] * (1.0f / CC);
}

// ---------- Kernel 4: intra loss per image ----------
__global__ __launch_bounds__(256) void k_loss_in(const float* __restrict__ per_region,
                                                 const int* __restrict__ count,
                                                 float* __restrict__ loss_in) {
    int b = blockIdx.x;
    int n = count[b];
    __shared__ float sm[256];
    float s = 0.f;
    for (int k = threadIdx.x; k < n; k += 256) s += per_region[b * KK + k];
    sm[threadIdx.x] = s;
    __syncthreads();
    for (int d = 128; d > 0; d >>= 1) {
        if (threadIdx.x < d) sm[threadIdx.x] += sm[threadIdx.x + d];
        __syncthreads();
    }
    if (threadIdx.x == 0) loss_in[b] = (n > 0) ? sm[0] / (float)n : 0.f;
}

// ---------- Kernel 5: pairwise hinge partials (GOUT blocks / image) ----------
__global__ __launch_bounds__(256) void k_pairs(const float* __restrict__ means,
                                               const int* __restrict__ count,
                                               float* __restrict__ partial) {
    int b = blockIdx.x / GOUT;
    int g = blockIdx.x % GOUT;
    int n = count[b];
    const float* mf = means + (size_t)b * KK * 49;
    __shared__ float mi[49];
    __shared__ float sm[256];
    float acc = 0.f;
    for (int i = g; i < n; i += GOUT) {
        __syncthreads();
        if (threadIdx.x < 49) mi[threadIdx.x] = mf[(size_t)i * 49 + threadIdx.x];
        __syncthreads();
        for (int j = i + 1 + (int)threadIdx.x; j < n; j += 256) {
            const float* mj = mf + (size_t)j * 49;
            float d2 = 0.f;
            #pragma unroll
            for (int d = 0; d < 49; ++d) {
                float t = mi[d] - mj[d];
                d2 += t * t;
            }
            float dd = sqrtf(d2);
            if (dd < 1.f) acc += 1.f - dd;
        }
    }
    sm[threadIdx.x] = acc;
    __syncthreads();
    for (int d = 128; d > 0; d >>= 1) {
        if (threadIdx.x < d) sm[threadIdx.x] += sm[threadIdx.x + d];
        __syncthreads();
    }
    if (threadIdx.x == 0) partial[b * GOUT + g] = sm[0];
}

// ---------- Kernel 6: finalize ----------
__global__ __launch_bounds__(64) void k_final(const float* __restrict__ loss_in,
                                              const float* __restrict__ partial,
                                              const int* __restrict__ count,
                                              float* __restrict__ out) {
    int lane = threadIdx.x;
    float li = 0.f, lo = 0.f;
    if (lane < BB) {
        li = loss_in[lane];
        float s = 0.f;
        #pragma unroll
        for (int g = 0; g < GOUT; ++g) s += partial[lane * GOUT + g];
        float n = (float)count[lane];
        float npairs = n * (n - 1.f) * 0.5f;
        lo = (npairs > 0.f) ? s / npairs : 0.f;
    }
    #pragma unroll
    for (int d = 4; d > 0; d >>= 1) {
        li += __shfl_down(li, d);
        lo += __shfl_down(lo, d);
    }
    if (lane == 0) out[0] = 0.5f * (li * (1.0f / BB)) + 1.0f * (lo * (1.0f / BB));
}

extern "C" void kernel_launch(void* const* d_in, const int* in_sizes, int n_in,
                              void* d_out, int out_size, void* d_ws, size_t ws_size,
                              hipStream_t stream) {
    const float* fm = (const float*)d_in[0];   // [8,128,192,192] f32
    const float* hm = (const float*)d_in[1];   // [8,1,192,192]  f32
    float* out = (float*)d_out;

    char* ws = (char*)d_ws;
    size_t off = 0;
    auto alloc = [&](size_t bytes) -> void* {
        void* p = ws + off;
        off += (bytes + 255) & ~(size_t)255;
        return p;
    };
    unsigned char* flags = (unsigned char*)alloc((size_t)BB * HWSZ);           // 288 KB
    int* peaks          = (int*)alloc((size_t)BB * KK * sizeof(int));          // 32 KB
    int* count          = (int*)alloc((size_t)BB * sizeof(int));
    float* means        = (float*)alloc((size_t)BB * KK * 49 * sizeof(float)); // 1.57 MB
    float* per_region   = (float*)alloc((size_t)BB * KK * sizeof(float));      // 32 KB
    float* loss_in      = (float*)alloc((size_t)BB * sizeof(float));
    float* partial      = (float*)alloc((size_t)BB * GOUT * sizeof(float));

    k_flags<<<(BB * HWSZ + 255) / 256, 256, 0, stream>>>(hm, flags);
    k_compact<<<BB, 64, 0, stream>>>(flags, peaks, count);
    k_region<<<BB * KK, 128, 0, stream>>>(fm, peaks, count, means, per_region);
    k_loss_in<<<BB, 256, 0, stream>>>(per_region, count, loss_in);
    k_pairs<<<BB * GOUT, 256, 0, stream>>>(means, count, partial);
    k_final<<<1, 64, 0, stream>>>(loss_in, partial, count, out);
}

// Round 3
// 100.742 us; speedup vs baseline: 1.4778x; 1.2749x over previous
//
#include <hip/hip_runtime.h>
#include <hip/hip_bf16.h>

#define BB 8
#define CC 128
#define HH 192
#define WW 192
#define HWSZ (HH*WW)
#define KK 1024
#define HALF 3
#define GOUT 32
#define LDP 129   // padded channel stride

// ---------- Kernel 1: peak flags (local max of 3x3, value > 0) ----------
__global__ void k_flags(const float* __restrict__ hm, unsigned char* __restrict__ flags) {
    int idx = blockIdx.x * blockDim.x + threadIdx.x;
    if (idx >= BB * HWSZ) return;
    int b = idx / HWSZ;
    int p = idx % HWSZ;
    int y = p / WW, x = p % WW;
    const float* h = hm + (size_t)b * HWSZ;
    float v = h[p];
    unsigned char f = 0;
    if (v > 0.f) {
        bool peak = true;
        #pragma unroll
        for (int dy = -1; dy <= 1; ++dy) {
            #pragma unroll
            for (int dx = -1; dx <= 1; ++dx) {
                int yy = y + dy, xx = x + dx;
                if (yy < 0 || yy >= HH || xx < 0 || xx >= WW) continue;
                if (h[yy * WW + xx] > v) peak = false;
            }
        }
        f = peak ? 1 : 0;
    }
    flags[idx] = f;
}

// ---------- Kernel 2: deterministic ordered compaction (1 wave / image) ----------
__global__ __launch_bounds__(64) void k_compact(const unsigned char* __restrict__ flags,
                                                int* __restrict__ peaks,
                                                int* __restrict__ count) {
    int b = blockIdx.x;
    int lane = threadIdx.x;  // 0..63
    const unsigned char* f = flags + (size_t)b * HWSZ;
    int base = 0;
    uint4 pre = *reinterpret_cast<const uint4*>(f + lane * 16);
    for (int it = 0; it < HWSZ / 1024; ++it) {
        uint4 v = pre;
        if (it + 1 < HWSZ / 1024)
            pre = *reinterpret_cast<const uint4*>(f + (it + 1) * 1024 + lane * 16);
        unsigned int wv[4] = {v.x, v.y, v.z, v.w};
        int cnt = 0;
        #pragma unroll
        for (int q = 0; q < 4; ++q) cnt += __popc(wv[q] & 0x01010101u);
        int incl = cnt;
        #pragma unroll
        for (int d = 1; d < 64; d <<= 1) {
            int t = __shfl_up(incl, d);
            if (lane >= d) incl += t;
        }
        int s = base + (incl - cnt);
        int pbase = it * 1024 + lane * 16;
        #pragma unroll
        for (int q = 0; q < 4; ++q) {
            unsigned int w = wv[q];
            #pragma unroll
            for (int j = 0; j < 4; ++j) {
                if ((w >> (8 * j)) & 1u) {
                    if (s < KK) peaks[b * KK + s] = pbase + q * 4 + j;
                    ++s;
                }
            }
        }
        base += __shfl(incl, 63);
    }
    if (lane == 0) count[b] = (base < KK) ? base : KK;
}

// ---------- Kernel 3: per-peak region — vectorized aligned-window staging ----------
// Per (ch,row) segment (28B), 4 lanes each load one aligned float4 from a 16-float
// window guaranteed to cover the valid span. 56 dwordx4/block vs 98 scalar gathers.
__global__ __launch_bounds__(256) void k_region(const float* __restrict__ fm,
                                                const int* __restrict__ peaks,
                                                const int* __restrict__ count,
                                                float* __restrict__ means,
                                                float* __restrict__ per_region) {
    int b = blockIdx.x / KK;
    int k = blockIdx.x % KK;
    if (k >= count[b]) return;
    int p = peaks[b * KK + k];
    int r = p / WW, c = p % WW;  // region rows come from c, cols from r (x/y swap)
    int tid = threadIdx.x;
    const float* F = fm + (size_t)b * CC * HWSZ;

    __shared__ float lds[49 * LDP];   // [pos][ch]
    __shared__ float ms[49];
    __shared__ float aux[256];        // reused: pm[49][4] then part[256]

    bool edge = (r < HALF) || (r > WW - 1 - HALF) || (c < HALF) || (c > HH - 1 - HALF);
    if (edge) {
        for (int i = tid; i < 49 * LDP; i += 256) lds[i] = 0.f;
        __syncthreads();
    }

    // staging: segment sIdx = ch + 128*a; group (4 lanes) per segment
    int o = r - HALF;                       // first needed column
    int a0 = o & ~3;                        // 16B-aligned window start
    a0 = (a0 < 0) ? 0 : a0;
    a0 = (a0 > WW - 16) ? (WW - 16) : a0;
    int sub = tid & 3;
    int grp = tid >> 2;                     // 0..63
    #pragma unroll
    for (int it = 0; it < 14; ++it) {
        int sIdx = it * 64 + grp;           // 0..895
        int ch = sIdx & 127;
        int a = sIdx >> 7;                  // 0..6
        int frow = c + a - HALF;
        if (frow >= 0 && frow < HH) {
            const float* rowp = F + (size_t)ch * HWSZ + frow * WW;
            float4 v = *reinterpret_cast<const float4*>(rowp + a0 + sub * 4);
            int bb0 = a0 + sub * 4 - o;     // region col of v.x
            float vv[4] = {v.x, v.y, v.z, v.w};
            #pragma unroll
            for (int j = 0; j < 4; ++j) {
                int bb2 = bb0 + j;
                if (bb2 >= 0 && bb2 <= 6) lds[(a * 7 + bb2) * LDP + ch] = vv[j];
            }
        }
    }
    __syncthreads();

    // means: 196 threads, each sums 32 channels of one position
    if (tid < 196) {
        int pos = tid >> 2, q = tid & 3;
        const float* row = lds + pos * LDP + q * 32;
        float s = 0.f;
        #pragma unroll
        for (int i = 0; i < 32; ++i) s += row[i];
        aux[pos * 4 + q] = s;
    }
    __syncthreads();
    if (tid < 49) {
        float m = (aux[tid * 4] + aux[tid * 4 + 1] + aux[tid * 4 + 2] + aux[tid * 4 + 3]) * (1.0f / CC);
        ms[tid] = m;
        means[((size_t)b * KK + k) * 49 + tid] = m;
    }
    __syncthreads();

    // d2: 2 threads per channel split even/odd positions
    {
        int ch = tid & 127, h = tid >> 7;
        float d2p = 0.f;
        for (int pos = h; pos < 49; pos += 2) {
            float d = lds[pos * LDP + ch] - ms[pos];
            d2p += d * d;
        }
        aux[tid] = d2p;
    }
    __syncthreads();
    if (tid < 128) {
        float d2 = aux[tid] + aux[tid + 128];
        float acc = (d2 > 0.f) ? sqrtf(d2) : 0.f;
        __syncthreads();
        aux[tid] = acc;
    } else {
        __syncthreads();
    }
    __syncthreads();
    #pragma unroll
    for (int d = 64; d > 0; d >>= 1) {
        if (tid < d) aux[tid] += aux[tid + d];
        __syncthreads();
    }
    if (tid == 0) per_region[b * KK + k] = aux[0] * (1.0f / CC);
}

// ---------- Kernel 4: intra loss per image ----------
__global__ __launch_bounds__(256) void k_loss_in(const float* __restrict__ per_region,
                                                 const int* __restrict__ count,
                                                 float* __restrict__ loss_in) {
    int b = blockIdx.x;
    int n = count[b];
    __shared__ float sm[256];
    float s = 0.f;
    for (int k = threadIdx.x; k < n; k += 256) s += per_region[b * KK + k];
    sm[threadIdx.x] = s;
    __syncthreads();
    for (int d = 128; d > 0; d >>= 1) {
        if (threadIdx.x < d) sm[threadIdx.x] += sm[threadIdx.x + d];
        __syncthreads();
    }
    if (threadIdx.x == 0) loss_in[b] = (n > 0) ? sm[0] / (float)n : 0.f;
}

// ---------- Kernel 5: pairwise hinge partials (GOUT blocks / image) ----------
__global__ __launch_bounds__(256) void k_pairs(const float* __restrict__ means,
                                               const int* __restrict__ count,
                                               float* __restrict__ partial) {
    int b = blockIdx.x / GOUT;
    int g = blockIdx.x % GOUT;
    int n = count[b];
    const float* mf = means + (size_t)b * KK * 49;
    __shared__ float mi[49];
    __shared__ float sm[256];
    float acc = 0.f;
    for (int i = g; i < n; i += GOUT) {
        __syncthreads();
        if (threadIdx.x < 49) mi[threadIdx.x] = mf[(size_t)i * 49 + threadIdx.x];
        __syncthreads();
        for (int j = i + 1 + (int)threadIdx.x; j < n; j += 256) {
            const float* mj = mf + (size_t)j * 49;
            float d2 = 0.f;
            #pragma unroll
            for (int d = 0; d < 49; ++d) {
                float t = mi[d] - mj[d];
                d2 += t * t;
            }
            float dd = sqrtf(d2);
            if (dd < 1.f) acc += 1.f - dd;
        }
    }
    sm[threadIdx.x] = acc;
    __syncthreads();
    for (int d = 128; d > 0; d >>= 1) {
        if (threadIdx.x < d) sm[threadIdx.x] += sm[threadIdx.x + d];
        __syncthreads();
    }
    if (threadIdx.x == 0) partial[b * GOUT + g] = sm[0];
}

// ---------- Kernel 6: finalize ----------
__global__ __launch_bounds__(64) void k_final(const float* __restrict__ loss_in,
                                              const float* __restrict__ partial,
                                              const int* __restrict__ count,
                                              float* __restrict__ out) {
    int lane = threadIdx.x;
    float li = 0.f, lo = 0.f;
    if (lane < BB) {
        li = loss_in[lane];
        float s = 0.f;
        #pragma unroll
        for (int g = 0; g < GOUT; ++g) s += partial[lane * GOUT + g];
        float n = (float)count[lane];
        float npairs = n * (n - 1.f) * 0.5f;
        lo = (npairs > 0.f) ? s / npairs : 0.f;
    }
    #pragma unroll
    for (int d = 4; d > 0; d >>= 1) {
        li += __shfl_down(li, d);
        lo += __shfl_down(lo, d);
    }
    if (lane == 0) out[0] = 0.5f * (li * (1.0f / BB)) + 1.0f * (lo * (1.0f / BB));
}

extern "C" void kernel_launch(void* const* d_in, const int* in_sizes, int n_in,
                              void* d_out, int out_size, void* d_ws, size_t ws_size,
                              hipStream_t stream) {
    const float* fm = (const float*)d_in[0];   // [8,128,192,192] f32
    const float* hm = (const float*)d_in[1];   // [8,1,192,192]  f32
    float* out = (float*)d_out;

    char* ws = (char*)d_ws;
    size_t off = 0;
    auto alloc = [&](size_t bytes) -> void* {
        void* p = ws + off;
        off += (bytes + 255) & ~(size_t)255;
        return p;
    };
    unsigned char* flags = (unsigned char*)alloc((size_t)BB * HWSZ);
    int* peaks          = (int*)alloc((size_t)BB * KK * sizeof(int));
    int* count          = (int*)alloc((size_t)BB * sizeof(int));
    float* means        = (float*)alloc((size_t)BB * KK * 49 * sizeof(float));
    float* per_region   = (float*)alloc((size_t)BB * KK * sizeof(float));
    float* loss_in      = (float*)alloc((size_t)BB * sizeof(float));
    float* partial      = (float*)alloc((size_t)BB * GOUT * sizeof(float));

    k_flags<<<(BB * HWSZ + 255) / 256, 256, 0, stream>>>(hm, flags);
    k_compact<<<BB, 64, 0, stream>>>(flags, peaks, count);
    k_region<<<BB * KK, 256, 0, stream>>>(fm, peaks, count, means, per_region);
    k_loss_in<<<BB, 256, 0, stream>>>(per_region, count, loss_in);
    k_pairs<<<BB * GOUT, 256, 0, stream>>>(means, count, partial);
    k_final<<<1, 64, 0, stream>>>(loss_in, partial, count, out);
}

// Round 4
// 84.677 us; speedup vs baseline: 1.7582x; 1.1897x over previous
//
#include <hip/hip_runtime.h>
#include <hip/hip_bf16.h>

#define BB 8
#define CC 128
#define HH 192
#define WW 192
#define HWSZ (HH*WW)
#define KK 1024
#define HALF 3
#define GOUT 32
#define LDP 129   // padded channel stride

// ---------- Kernel 1: peak flags (local max of 3x3, value > 0) ----------
__global__ void k_flags(const float* __restrict__ hm, unsigned char* __restrict__ flags) {
    int idx = blockIdx.x * blockDim.x + threadIdx.x;
    if (idx >= BB * HWSZ) return;
    int b = idx / HWSZ;
    int p = idx % HWSZ;
    int y = p / WW, x = p % WW;
    const float* h = hm + (size_t)b * HWSZ;
    float v = h[p];
    unsigned char f = 0;
    if (v > 0.f) {
        bool peak = true;
        #pragma unroll
        for (int dy = -1; dy <= 1; ++dy) {
            #pragma unroll
            for (int dx = -1; dx <= 1; ++dx) {
                int yy = y + dy, xx = x + dx;
                if (yy < 0 || yy >= HH || xx < 0 || xx >= WW) continue;
                if (h[yy * WW + xx] > v) peak = false;
            }
        }
        f = peak ? 1 : 0;
    }
    flags[idx] = f;
}

// ---------- Kernel 2: deterministic ordered compaction (1 wave / image) ----------
__global__ __launch_bounds__(64) void k_compact(const unsigned char* __restrict__ flags,
                                                int* __restrict__ peaks,
                                                int* __restrict__ count) {
    int b = blockIdx.x;
    int lane = threadIdx.x;  // 0..63
    const unsigned char* f = flags + (size_t)b * HWSZ;
    int base = 0;
    uint4 pre = *reinterpret_cast<const uint4*>(f + lane * 16);
    for (int it = 0; it < HWSZ / 1024; ++it) {
        uint4 v = pre;
        if (it + 1 < HWSZ / 1024)
            pre = *reinterpret_cast<const uint4*>(f + (it + 1) * 1024 + lane * 16);
        unsigned int wv[4] = {v.x, v.y, v.z, v.w};
        int cnt = 0;
        #pragma unroll
        for (int q = 0; q < 4; ++q) cnt += __popc(wv[q] & 0x01010101u);
        int incl = cnt;
        #pragma unroll
        for (int d = 1; d < 64; d <<= 1) {
            int t = __shfl_up(incl, d);
            if (lane >= d) incl += t;
        }
        int s = base + (incl - cnt);
        int pbase = it * 1024 + lane * 16;
        #pragma unroll
        for (int q = 0; q < 4; ++q) {
            unsigned int w = wv[q];
            #pragma unroll
            for (int j = 0; j < 4; ++j) {
                if ((w >> (8 * j)) & 1u) {
                    if (s < KK) peaks[b * KK + s] = pbase + q * 4 + j;
                    ++s;
                }
            }
        }
        base += __shfl(incl, 63);
    }
    if (lane == 0) count[b] = (base < KK) ? base : KK;
}

// ---------- Kernel 3: per-peak region — reg-staged loads + k-major remap ----------
// All 14 float4 loads issue into VGPRs first (>=14 in flight per wave), LDS
// writes afterwards. Block remap is k-major so active blocks are contiguous
// from blockIdx 0 and spread across all CUs.
__global__ __launch_bounds__(256) void k_region(const float* __restrict__ fm,
                                                const int* __restrict__ peaks,
                                                const int* __restrict__ count,
                                                float* __restrict__ means,
                                                float* __restrict__ per_region) {
    int bid = blockIdx.x;
    int b = bid & (BB - 1);
    int k = bid >> 3;
    if (k >= count[b]) return;
    int p = peaks[b * KK + k];
    int r = p / WW, c = p % WW;  // region rows come from c, cols from r (x/y swap)
    int tid = threadIdx.x;
    const float* F = fm + (size_t)b * CC * HWSZ;

    __shared__ float lds[49 * LDP];   // [pos][ch]
    __shared__ float ms[49];
    __shared__ float aux[256];
    __shared__ float wsum[2];

    bool edge = (r < HALF) || (r > WW - 1 - HALF) || (c < HALF) || (c > HH - 1 - HALF);
    if (edge) {
        for (int i = tid; i < 49 * LDP; i += 256) lds[i] = 0.f;
        __syncthreads();
    }

    // aligned 16-float window covering the valid 7-col span
    int o = r - HALF;
    int a0 = o & ~3;
    a0 = (a0 < 0) ? 0 : a0;
    a0 = (a0 > WW - 16) ? (WW - 16) : a0;
    int sub = tid & 3;
    int grp = tid >> 2;   // 0..63: segment group (4 lanes per (ch,row) segment)

    // phase 1: issue ALL loads to registers (fully unrolled -> static idx)
    float4 vbuf[14];
    #pragma unroll
    for (int it = 0; it < 14; ++it) {
        int sIdx = it * 64 + grp;        // 0..895 = ch + 128*a
        int ch = sIdx & 127;
        int a = sIdx >> 7;
        int frow = c + a - HALF;
        float4 v = make_float4(0.f, 0.f, 0.f, 0.f);
        if (frow >= 0 && frow < HH)
            v = *reinterpret_cast<const float4*>(F + (size_t)ch * HWSZ + frow * WW + a0 + sub * 4);
        vbuf[it] = v;
    }

    // phase 2: LDS writes (zeros are harmless on edge blocks — tile pre-zeroed)
    int bb0 = a0 + sub * 4 - o;          // region col of vbuf.x
    #pragma unroll
    for (int it = 0; it < 14; ++it) {
        int sIdx = it * 64 + grp;
        int ch = sIdx & 127;
        int a = sIdx >> 7;
        float vv[4] = {vbuf[it].x, vbuf[it].y, vbuf[it].z, vbuf[it].w};
        #pragma unroll
        for (int j = 0; j < 4; ++j) {
            int bb2 = bb0 + j;
            if (bb2 >= 0 && bb2 <= 6) lds[(a * 7 + bb2) * LDP + ch] = vv[j];
        }
    }
    __syncthreads();

    // means: 196 threads, each sums 32 channels of one position
    if (tid < 196) {
        int pos = tid >> 2, q = tid & 3;
        const float* row = lds + pos * LDP + q * 32;
        float s = 0.f;
        #pragma unroll
        for (int i = 0; i < 32; ++i) s += row[i];
        aux[pos * 4 + q] = s;
    }
    __syncthreads();
    if (tid < 49) {
        float m = (aux[tid * 4] + aux[tid * 4 + 1] + aux[tid * 4 + 2] + aux[tid * 4 + 3]) * (1.0f / CC);
        ms[tid] = m;
        means[((size_t)b * KK + k) * 49 + tid] = m;
    }
    __syncthreads();

    // d2: 2 threads per channel split even/odd positions
    {
        int ch = tid & 127, h = tid >> 7;
        float d2p = 0.f;
        for (int pos = h; pos < 49; pos += 2) {
            float d = lds[pos * LDP + ch] - ms[pos];
            d2p += d * d;
        }
        aux[tid] = d2p;
    }
    __syncthreads();
    float acc = 0.f;
    if (tid < 128) {
        float d2 = aux[tid] + aux[tid + 128];
        acc = (d2 > 0.f) ? sqrtf(d2) : 0.f;
    }
    #pragma unroll
    for (int dlt = 32; dlt > 0; dlt >>= 1) acc += __shfl_down(acc, dlt);
    if (tid < 128 && (tid & 63) == 0) wsum[tid >> 6] = acc;
    __syncthreads();
    if (tid == 0) per_region[b * KK + k] = (wsum[0] + wsum[1]) * (1.0f / CC);
}

// ---------- Kernel 4: intra loss per image ----------
__global__ __launch_bounds__(256) void k_loss_in(const float* __restrict__ per_region,
                                                 const int* __restrict__ count,
                                                 float* __restrict__ loss_in) {
    int b = blockIdx.x;
    int n = count[b];
    __shared__ float sm[256];
    float s = 0.f;
    for (int k = threadIdx.x; k < n; k += 256) s += per_region[b * KK + k];
    sm[threadIdx.x] = s;
    __syncthreads();
    for (int d = 128; d > 0; d >>= 1) {
        if (threadIdx.x < d) sm[threadIdx.x] += sm[threadIdx.x + d];
        __syncthreads();
    }
    if (threadIdx.x == 0) loss_in[b] = (n > 0) ? sm[0] / (float)n : 0.f;
}

// ---------- Kernel 5: pairwise hinge partials (GOUT blocks / image) ----------
__global__ __launch_bounds__(256) void k_pairs(const float* __restrict__ means,
                                               const int* __restrict__ count,
                                               float* __restrict__ partial) {
    int b = blockIdx.x / GOUT;
    int g = blockIdx.x % GOUT;
    int n = count[b];
    const float* mf = means + (size_t)b * KK * 49;
    __shared__ float mi[49];
    __shared__ float sm[256];
    float acc = 0.f;
    for (int i = g; i < n; i += GOUT) {
        __syncthreads();
        if (threadIdx.x < 49) mi[threadIdx.x] = mf[(size_t)i * 49 + threadIdx.x];
        __syncthreads();
        for (int j = i + 1 + (int)threadIdx.x; j < n; j += 256) {
            const float* mj = mf + (size_t)j * 49;
            float d2 = 0.f;
            #pragma unroll
            for (int d = 0; d < 49; ++d) {
                float t = mi[d] - mj[d];
                d2 += t * t;
            }
            float dd = sqrtf(d2);
            if (dd < 1.f) acc += 1.f - dd;
        }
    }
    sm[threadIdx.x] = acc;
    __syncthreads();
    for (int d = 128; d > 0; d >>= 1) {
        if (threadIdx.x < d) sm[threadIdx.x] += sm[threadIdx.x + d];
        __syncthreads();
    }
    if (threadIdx.x == 0) partial[b * GOUT + g] = sm[0];
}

// ---------- Kernel 6: finalize ----------
__global__ __launch_bounds__(64) void k_final(const float* __restrict__ loss_in,
                                              const float* __restrict__ partial,
                                              const int* __restrict__ count,
                                              float* __restrict__ out) {
    int lane = threadIdx.x;
    float li = 0.f, lo = 0.f;
    if (lane < BB) {
        li = loss_in[lane];
        float s = 0.f;
        #pragma unroll
        for (int g = 0; g < GOUT; ++g) s += partial[lane * GOUT + g];
        float n = (float)count[lane];
        float npairs = n * (n - 1.f) * 0.5f;
        lo = (npairs > 0.f) ? s / npairs : 0.f;
    }
    #pragma unroll
    for (int d = 4; d > 0; d >>= 1) {
        li += __shfl_down(li, d);
        lo += __shfl_down(lo, d);
    }
    if (lane == 0) out[0] = 0.5f * (li * (1.0f / BB)) + 1.0f * (lo * (1.0f / BB));
}

extern "C" void kernel_launch(void* const* d_in, const int* in_sizes, int n_in,
                              void* d_out, int out_size, void* d_ws, size_t ws_size,
                              hipStream_t stream) {
    const float* fm = (const float*)d_in[0];   // [8,128,192,192] f32
    const float* hm = (const float*)d_in[1];   // [8,1,192,192]  f32
    float* out = (float*)d_out;

    char* ws = (char*)d_ws;
    size_t off = 0;
    auto alloc = [&](size_t bytes) -> void* {
        void* p = ws + off;
        off += (bytes + 255) & ~(size_t)255;
        return p;
    };
    unsigned char* flags = (unsigned char*)alloc((size_t)BB * HWSZ);
    int* peaks          = (int*)alloc((size_t)BB * KK * sizeof(int));
    int* count          = (int*)alloc((size_t)BB * sizeof(int));
    float* means        = (float*)alloc((size_t)BB * KK * 49 * sizeof(float));
    float* per_region   = (float*)alloc((size_t)BB * KK * sizeof(float));
    float* loss_in      = (float*)alloc((size_t)BB * sizeof(float));
    float* partial      = (float*)alloc((size_t)BB * GOUT * sizeof(float));

    k_flags<<<(BB * HWSZ + 255) / 256, 256, 0, stream>>>(hm, flags);
    k_compact<<<BB, 64, 0, stream>>>(flags, peaks, count);
    k_region<<<BB * KK, 256, 0, stream>>>(fm, peaks, count, means, per_region);
    k_loss_in<<<BB, 256, 0, stream>>>(per_region, count, loss_in);
    k_pairs<<<BB * GOUT, 256, 0, stream>>>(means, count, partial);
    k_final<<<1, 64, 0, stream>>>(loss_in, partial, count, out);
}

// Round 5
// 63.656 us; speedup vs baseline: 2.3388x; 1.3302x over previous
//
#include <hip/hip_runtime.h>
#include <hip/hip_bf16.h>

#define BB 8
#define CC 128
#define HH 192
#define WW 192
#define HWSZ (HH*WW)
#define KK 1024
#define HALF 3
#define GOUT 32
#define LDP 129   // padded channel stride
#define NEGINF (-3.0e38f)

// ---------- Kernel 1: peak flags, one float4-quad of pixels per thread ----------
__global__ __launch_bounds__(256) void k_flags(const float* __restrict__ hm,
                                               unsigned char* __restrict__ flags) {
    int idx = blockIdx.x * 256 + threadIdx.x;      // 8*9216 = 73728 quads
    int b = idx / (HWSZ / 4);
    int q = idx % (HWSZ / 4);
    int y = q / (WW / 4);
    int x0 = (q % (WW / 4)) * 4;
    const float* h = hm + (size_t)b * HWSZ;

    float r[3][6];
    #pragma unroll
    for (int dy = 0; dy < 3; ++dy) {
        int yy = y + dy - 1;
        if (yy >= 0 && yy < HH) {
            const float* row = h + yy * WW;
            float4 v = *reinterpret_cast<const float4*>(row + x0);
            r[dy][1] = v.x; r[dy][2] = v.y; r[dy][3] = v.z; r[dy][4] = v.w;
            r[dy][0] = (x0 > 0) ? row[x0 - 1] : NEGINF;
            r[dy][5] = (x0 + 4 < WW) ? row[x0 + 4] : NEGINF;
        } else {
            #pragma unroll
            for (int j = 0; j < 6; ++j) r[dy][j] = NEGINF;
        }
    }
    uchar4 f;
    unsigned char* fp = &f.x;
    #pragma unroll
    for (int i = 0; i < 4; ++i) {
        float v = r[1][i + 1];
        float m = NEGINF;
        #pragma unroll
        for (int dy = 0; dy < 3; ++dy) {
            float m3 = fmaxf(fmaxf(r[dy][i], r[dy][i + 1]), r[dy][i + 2]);
            m = fmaxf(m, m3);
        }
        fp[i] = (v > 0.f && m <= v) ? 1 : 0;
    }
    *reinterpret_cast<uchar4*>(flags + (size_t)idx * 4) = f;
}

// ---------- Kernel 2: parallel deterministic compaction (1024 thr / image) ----------
__global__ __launch_bounds__(1024) void k_compact(const unsigned char* __restrict__ flags,
                                                  int* __restrict__ peaks,
                                                  int* __restrict__ count) {
    int b = blockIdx.x;
    int t = threadIdx.x;        // 0..1023
    int lane = t & 63, wid = t >> 6;   // 16 waves
    const unsigned int* fw = reinterpret_cast<const unsigned int*>(flags + (size_t)b * HWSZ);

    __shared__ int wt[16];

    unsigned int masks[9];
    int cnt = 0;
    #pragma unroll
    for (int u = 0; u < 9; ++u) {      // 9*1024 = 9216 words = 36864 bytes
        unsigned int w = fw[u * 1024 + t];
        masks[u] = w & 0x01010101u;
        cnt += __popc(masks[u]);
    }
    // wave inclusive scan
    int incl = cnt;
    #pragma unroll
    for (int d = 1; d < 64; d <<= 1) {
        int x = __shfl_up(incl, d);
        if (lane >= d) incl += x;
    }
    if (lane == 63) wt[wid] = incl;
    __syncthreads();
    if (t == 0) {
        int run = 0;
        #pragma unroll
        for (int w = 0; w < 16; ++w) { int x = wt[w]; wt[w] = run; run += x; }
        count[b] = (run < KK) ? run : KK;
    }
    __syncthreads();
    int s = wt[wid] + (incl - cnt);
    #pragma unroll
    for (int u = 0; u < 9; ++u) {
        unsigned int w = masks[u];
        #pragma unroll
        for (int j = 0; j < 4; ++j) {
            if ((w >> (8 * j)) & 1u) {
                if (s < KK) peaks[b * KK + s] = (u * 1024 + t) * 4 + j;
                ++s;
            }
        }
    }
}

// ---------- Kernel 3: per-peak region — reg-staged loads + k-major remap ----------
__global__ __launch_bounds__(256) void k_region(const float* __restrict__ fm,
                                                const int* __restrict__ peaks,
                                                const int* __restrict__ count,
                                                float* __restrict__ means,
                                                float* __restrict__ per_region) {
    int bid = blockIdx.x;
    int b = bid & (BB - 1);
    int k = bid >> 3;
    if (k >= count[b]) return;
    int p = peaks[b * KK + k];
    int r = p / WW, c = p % WW;  // region rows come from c, cols from r (x/y swap)
    int tid = threadIdx.x;
    const float* F = fm + (size_t)b * CC * HWSZ;

    __shared__ float lds[49 * LDP];   // [pos][ch]
    __shared__ float ms[49];
    __shared__ float aux[256];
    __shared__ float wsum[2];

    bool edge = (r < HALF) || (r > WW - 1 - HALF) || (c < HALF) || (c > HH - 1 - HALF);
    if (edge) {
        for (int i = tid; i < 49 * LDP; i += 256) lds[i] = 0.f;
        __syncthreads();
    }

    int o = r - HALF;
    int a0 = o & ~3;
    a0 = (a0 < 0) ? 0 : a0;
    a0 = (a0 > WW - 16) ? (WW - 16) : a0;
    int sub = tid & 3;
    int grp = tid >> 2;

    float4 vbuf[14];
    #pragma unroll
    for (int it = 0; it < 14; ++it) {
        int sIdx = it * 64 + grp;
        int ch = sIdx & 127;
        int a = sIdx >> 7;
        int frow = c + a - HALF;
        float4 v = make_float4(0.f, 0.f, 0.f, 0.f);
        if (frow >= 0 && frow < HH)
            v = *reinterpret_cast<const float4*>(F + (size_t)ch * HWSZ + frow * WW + a0 + sub * 4);
        vbuf[it] = v;
    }

    int bb0 = a0 + sub * 4 - o;
    #pragma unroll
    for (int it = 0; it < 14; ++it) {
        int sIdx = it * 64 + grp;
        int ch = sIdx & 127;
        int a = sIdx >> 7;
        float vv[4] = {vbuf[it].x, vbuf[it].y, vbuf[it].z, vbuf[it].w};
        #pragma unroll
        for (int j = 0; j < 4; ++j) {
            int bb2 = bb0 + j;
            if (bb2 >= 0 && bb2 <= 6) lds[(a * 7 + bb2) * LDP + ch] = vv[j];
        }
    }
    __syncthreads();

    if (tid < 196) {
        int pos = tid >> 2, q = tid & 3;
        const float* row = lds + pos * LDP + q * 32;
        float s = 0.f;
        #pragma unroll
        for (int i = 0; i < 32; ++i) s += row[i];
        aux[pos * 4 + q] = s;
    }
    __syncthreads();
    if (tid < 49) {
        float m = (aux[tid * 4] + aux[tid * 4 + 1] + aux[tid * 4 + 2] + aux[tid * 4 + 3]) * (1.0f / CC);
        ms[tid] = m;
        means[((size_t)b * KK + k) * 49 + tid] = m;
    }
    __syncthreads();

    {
        int ch = tid & 127, h = tid >> 7;
        float d2p = 0.f;
        for (int pos = h; pos < 49; pos += 2) {
            float d = lds[pos * LDP + ch] - ms[pos];
            d2p += d * d;
        }
        aux[tid] = d2p;
    }
    __syncthreads();
    float acc = 0.f;
    if (tid < 128) {
        float d2 = aux[tid] + aux[tid + 128];
        acc = (d2 > 0.f) ? sqrtf(d2) : 0.f;
    }
    #pragma unroll
    for (int dlt = 32; dlt > 0; dlt >>= 1) acc += __shfl_down(acc, dlt);
    if (tid < 128 && (tid & 63) == 0) wsum[tid >> 6] = acc;
    __syncthreads();
    if (tid == 0) per_region[b * KK + k] = (wsum[0] + wsum[1]) * (1.0f / CC);
}

// ---------- Kernel 4: pairwise hinge partials (GOUT blocks / image) ----------
__global__ __launch_bounds__(256) void k_pairs(const float* __restrict__ means,
                                               const int* __restrict__ count,
                                               float* __restrict__ partial) {
    int b = blockIdx.x / GOUT;
    int g = blockIdx.x % GOUT;
    int n = count[b];
    const float* mf = means + (size_t)b * KK * 49;
    __shared__ float mi[49];
    __shared__ float sm[256];
    float acc = 0.f;
    for (int i = g; i < n; i += GOUT) {
        __syncthreads();
        if (threadIdx.x < 49) mi[threadIdx.x] = mf[(size_t)i * 49 + threadIdx.x];
        __syncthreads();
        for (int j = i + 1 + (int)threadIdx.x; j < n; j += 256) {
            const float* mj = mf + (size_t)j * 49;
            float d2 = 0.f;
            #pragma unroll
            for (int d = 0; d < 49; ++d) {
                float t = mi[d] - mj[d];
                d2 += t * t;
            }
            float dd = sqrtf(d2);
            if (dd < 1.f) acc += 1.f - dd;
        }
    }
    sm[threadIdx.x] = acc;
    __syncthreads();
    for (int d = 128; d > 0; d >>= 1) {
        if (threadIdx.x < d) sm[threadIdx.x] += sm[threadIdx.x + d];
        __syncthreads();
    }
    if (threadIdx.x == 0) partial[b * GOUT + g] = sm[0];
}

// ---------- Kernel 5: fused loss_in reduce + pairs reduce + output ----------
__global__ __launch_bounds__(256) void k_final(const float* __restrict__ per_region,
                                               const float* __restrict__ partial,
                                               const int* __restrict__ count,
                                               float* __restrict__ out) {
    int tid = threadIdx.x;
    int b = tid >> 5;           // 32 threads per image
    int sl = tid & 31;
    int n = count[b];

    __shared__ float lds_li[BB];
    __shared__ float lds_lo[BB];

    // intra loss: 32-thread group sums per_region[b][0..n)
    float s = 0.f;
    for (int i = sl; i < n; i += 32) s += per_region[b * KK + i];
    #pragma unroll
    for (int m = 16; m > 0; m >>= 1) s += __shfl_xor(s, m);
    if (sl == 0) lds_li[b] = (n > 0) ? s / (float)n : 0.f;

    // inter loss: partial[b][g], g = sl
    float v = partial[b * GOUT + sl];
    #pragma unroll
    for (int m = 16; m > 0; m >>= 1) v += __shfl_xor(v, m);
    if (sl == 0) {
        float fn = (float)n;
        float npairs = fn * (fn - 1.f) * 0.5f;
        lds_lo[b] = (npairs > 0.f) ? v / npairs : 0.f;
    }
    __syncthreads();
    if (tid == 0) {
        float li = 0.f, lo = 0.f;
        #pragma unroll
        for (int i = 0; i < BB; ++i) { li += lds_li[i]; lo += lds_lo[i]; }
        out[0] = 0.5f * (li * (1.0f / BB)) + 1.0f * (lo * (1.0f / BB));
    }
}

extern "C" void kernel_launch(void* const* d_in, const int* in_sizes, int n_in,
                              void* d_out, int out_size, void* d_ws, size_t ws_size,
                              hipStream_t stream) {
    const float* fm = (const float*)d_in[0];   // [8,128,192,192] f32
    const float* hm = (const float*)d_in[1];   // [8,1,192,192]  f32
    float* out = (float*)d_out;

    char* ws = (char*)d_ws;
    size_t off = 0;
    auto alloc = [&](size_t bytes) -> void* {
        void* p = ws + off;
        off += (bytes + 255) & ~(size_t)255;
        return p;
    };
    unsigned char* flags = (unsigned char*)alloc((size_t)BB * HWSZ);
    int* peaks          = (int*)alloc((size_t)BB * KK * sizeof(int));
    int* count          = (int*)alloc((size_t)BB * sizeof(int));
    float* means        = (float*)alloc((size_t)BB * KK * 49 * sizeof(float));
    float* per_region   = (float*)alloc((size_t)BB * KK * sizeof(float));
    float* partial      = (float*)alloc((size_t)BB * GOUT * sizeof(float));

    k_flags<<<(BB * HWSZ / 4) / 256, 256, 0, stream>>>(hm, flags);
    k_compact<<<BB, 1024, 0, stream>>>(flags, peaks, count);
    k_region<<<BB * KK, 256, 0, stream>>>(fm, peaks, count, means, per_region);
    k_pairs<<<BB * GOUT, 256, 0, stream>>>(means, count, partial);
    k_final<<<1, 256, 0, stream>>>(per_region, partial, count, out);
}